// Round 6
// baseline (18750.667 us; speedup 1.0000x reference)
//
#include <hip/hip_runtime.h>
#include <hip/hip_bf16.h>

// Problem constants
#define V_ 32000
#define E_ 512
#define H_ 1024
#define B_ 16
#define T_ 256
#define H4_ 4096
#define BT_ 4096           // B*T = M for the GEMMs
#define LOGITS_N (131072000LL)  // B*T*V

typedef __attribute__((ext_vector_type(8))) short short8v;
typedef __attribute__((ext_vector_type(4))) float f32x4;

__device__ __forceinline__ ushort f2bf(float f) {
    __hip_bfloat16 h = __float2bfloat16(f);
    return *reinterpret_cast<ushort*>(&h);
}

// async global->LDS, 16B per lane. LDS dest = wave-uniform base + lane*16.
// Global source is per-lane. Const stripped via (void*) before the
// addrspace cast (single-step const+AS conversion may not compile);
// LDS side must be a true generic->AS3 addrspacecast (never via integer).
__device__ __forceinline__ void gload_lds16(const void* g, void* l) {
    __builtin_amdgcn_global_load_lds(
        (__attribute__((address_space(1))) void*)(void*)g,
        (__attribute__((address_space(3))) void*)l, 16, 0, 0);
}

// ---------------------------------------------------------------------------
// f32 -> bf16 conversion (vectorized, grid-stride)
// ---------------------------------------------------------------------------
__global__ __launch_bounds__(256) void cvt_bf16(const float* __restrict__ s,
                                                ushort* __restrict__ d, int n4) {
    for (int i = blockIdx.x * blockDim.x + threadIdx.x; i < n4;
         i += gridDim.x * blockDim.x) {
        float4 v = reinterpret_cast<const float4*>(s)[i];
        ushort4 o;
        o.x = f2bf(v.x); o.y = f2bf(v.y); o.z = f2bf(v.z); o.w = f2bf(v.w);
        reinterpret_cast<ushort4*>(d)[i] = o;
    }
}

// ---------------------------------------------------------------------------
// Embedding gather: A0[t*B + b][e] = bf16(emb[x[b][t]][e])
// ---------------------------------------------------------------------------
__global__ __launch_bounds__(128) void embed_k(const int* __restrict__ x,
                                               const float* __restrict__ emb,
                                               ushort* __restrict__ A0) {
    int bt = blockIdx.x;          // b*T + t
    int b = bt >> 8;
    int t = bt & 255;
    int row = t * B_ + b;
    int tok = x[bt];
    float4 v = reinterpret_cast<const float4*>(&emb[(size_t)tok * E_])[threadIdx.x];
    ushort4 o;
    o.x = f2bf(v.x); o.y = f2bf(v.y); o.z = f2bf(v.z); o.w = f2bf(v.w);
    reinterpret_cast<ushort4*>(&A0[(size_t)row * E_])[threadIdx.x] = o;
}

// ---------------------------------------------------------------------------
// bf16 GEMM, C[M,N] f32 = A[M,K] @ B[N,K]^T + bias1[n] (+ bias2[n])
// m97 structure: 128x128 tile, BK=32, linear LDS [128][32], staging via
// global_load_lds width=16, 4 waves (2x2), each wave 64x64 via 4x4 frags of
// mfma_f32_16x16x32_bf16.
// Grid: blockIdx.x = M-tile (FAST axis), blockIdx.y = N-tile: the 32 blocks
// sharing one B column-panel run concurrently -> B-tile fetched per XCD L2
// once and reused.
// A/B fragment k-layout: result invariant to the per-lane k permutation
// (A and B frags use identical index formulas; sum over k commutes).
// C/D layout (m89/m91 verified): col = lane&15, row = (lane>>4)*4 + reg.
// ---------------------------------------------------------------------------
__global__ __launch_bounds__(256) void gemm_bt(const ushort* __restrict__ A,
                                               const ushort* __restrict__ Bm,
                                               const float* __restrict__ bias1,
                                               const float* __restrict__ bias2,
                                               float* __restrict__ C,
                                               int M, int N, int K) {
    __shared__ ushort As[128][32];   // linear: global_load_lds dest
    __shared__ ushort Bs[128][32];

    const int tid = threadIdx.x;
    const int m0 = blockIdx.x * 128;   // M fast axis
    const int n0 = blockIdx.y * 128;

    const int w = tid >> 6;
    const int l = tid & 63;
    const int lm = l & 15;
    const int kg = l >> 4;           // 0..3
    const int wr = (w >> 1) * 64;    // wave row offset
    const int wc = (w & 1) * 64;     // wave col offset

    // staging source coords: lane l covers LDS row base + l/4, col (l&3)*8
    const int srow = l >> 2;         // 0..15
    const int scol = (l & 3) * 8;    // 0,8,16,24

    f32x4 acc[4][4];
#pragma unroll
    for (int m = 0; m < 4; ++m)
#pragma unroll
        for (int n = 0; n < 4; ++n) acc[m][n] = (f32x4)(0.f);

    for (int kt = 0; kt < K; kt += 32) {
        __syncthreads();
        // stage A and B tiles (16 KB): wave w rows [32w,32w+32), 2 chunks of 16
#pragma unroll
        for (int i = 0; i < 2; ++i) {
            int rbase = w * 32 + i * 16;
            gload_lds16(&A[(size_t)(m0 + rbase + srow) * K + kt + scol],
                        &As[rbase][0]);
            gload_lds16(&Bm[(size_t)(n0 + rbase + srow) * K + kt + scol],
                        &Bs[rbase][0]);
        }
        __syncthreads();   // drains vmcnt (compiler emits full waitcnt)

        short8v af[4], bfv[4];
#pragma unroll
        for (int m = 0; m < 4; ++m)
            af[m] = *reinterpret_cast<const short8v*>(&As[wr + m * 16 + lm][kg * 8]);
#pragma unroll
        for (int n = 0; n < 4; ++n)
            bfv[n] = *reinterpret_cast<const short8v*>(&Bs[wc + n * 16 + lm][kg * 8]);

#pragma unroll
        for (int m = 0; m < 4; ++m)
#pragma unroll
            for (int n = 0; n < 4; ++n)
                acc[m][n] = __builtin_amdgcn_mfma_f32_16x16x32_bf16(
                    af[m], bfv[n], acc[m][n], 0, 0, 0);
    }

#pragma unroll
    for (int n = 0; n < 4; ++n) {
        int col = n0 + wc + n * 16 + lm;
        float bs = bias1[col];
        if (bias2) bs += bias2[col];
#pragma unroll
        for (int m = 0; m < 4; ++m) {
            int r0 = m0 + wr + m * 16 + kg * 4;
#pragma unroll
            for (int j = 0; j < 4; ++j)
                C[(size_t)(r0 + j) * N + col] = acc[m][n][j] + bs;
        }
    }
}

// ---------------------------------------------------------------------------
// Diagonal LSTM step. Dispatch d: blocks 0..255 run layer-0 t=d (if d<256),
// blocks 256..511 run layer-1 t=d-1 (if d>=1). ys0[d-1] was written by the
// previous dispatch (same-stream kernel boundary = release/acquire).
//
// Layer 0 (block bx<256): owns jh in [bx*4,bx*4+4). Thread tid=g*64+jl*16+b
// computes dot(h0[b], Whh0[g*H+jh]) (1024) + xp0[t*B+b][g*H+jh].
// Layer 1 (block bx>=256): dot over [h1 ; ys0[t]] vs [Whh1 | Wih1] rows
// + (bih1+bhh1). The u*y half touches only global/L2 data, so it runs
// BEFORE the staging barrier (T14: latency-bound at 2 waves/SIMD); the
// first 2 float4 of each weight stream are prefetched pre-barrier too
// (loads can't be hoisted across __syncthreads by the compiler).
// Phase 2 (tid<64): nonlinearity, c/h update, y output.
//   L0 -> y0 f32 [T][B][H];  L1 -> outb bf16 [B][T][H] (FC GEMM A-layout).
// h double-buffered by t parity: t even reads ha writes hb; t odd reverse.
// ---------------------------------------------------------------------------
__global__ __launch_bounds__(256) void lstm_diag(
    const float* __restrict__ xp0,   // [T*B][4H]
    const float* __restrict__ Whh0,  // [4H][H]
    float* __restrict__ h0a, float* __restrict__ h0b,
    float* __restrict__ c0,
    float* __restrict__ y0,          // f32 [T][B][H]
    const float* __restrict__ Whh1,  // [4H][H]
    const float* __restrict__ Wih1,  // [4H][H]
    const float* __restrict__ bih1, const float* __restrict__ bhh1,
    float* __restrict__ h1a, float* __restrict__ h1b,
    float* __restrict__ c1,
    ushort* __restrict__ outb,       // bf16 [B][T][H]
    int d) {
    __shared__ float hs[16][1028];   // +4 pad: 2-way bank pattern (free, m136)
    __shared__ float gl[256];

    const int tid = threadIdx.x;
    const bool isL1 = blockIdx.x >= 256;
    const int t = isL1 ? (d - 1) : d;
    if (t < 0 || t >= T_) return;

    const int bxl = isL1 ? (blockIdx.x - 256) : blockIdx.x;

    const float* hin = isL1 ? ((t & 1) ? h1b : h1a) : ((t & 1) ? h0b : h0a);
    float* hout      = isL1 ? ((t & 1) ? h1a : h1b) : ((t & 1) ? h0a : h0b);
    float* cst       = isL1 ? c1 : c0;

    const int g = tid >> 6;
    const int jl = (tid >> 4) & 3;
    const int b = tid & 15;
    const int jh = (bxl << 2) + jl;
    const int grow = g * H_ + jh;

    // pointers (block-uniform branch selection)
    const float4* w4 = reinterpret_cast<const float4*>(
        isL1 ? &Whh1[(size_t)grow * H_] : &Whh0[(size_t)grow * H_]);
    const float4* u4 = reinterpret_cast<const float4*>(&Wih1[(size_t)grow * H_]);
    const float4* y4 = reinterpret_cast<const float4*>(
        &y0[((size_t)(t < 0 ? 0 : t) * B_ + b) * H_]);

    // prefetch first 2 float4 of the weight stream (pre-barrier issue)
    float4 pw0 = w4[0], pw1 = w4[1];

    // stage h_in [16][1024] f32 = 4096 float4 (256 per batch row), coalesced
    for (int i = tid; i < 4096; i += 256) {
        float4 v = reinterpret_cast<const float4*>(hin)[i];
        int bb = i >> 8;
        int kc = (i & 255) << 2;
        *reinterpret_cast<float4*>(&hs[bb][kc]) = v;
    }

    // L1 only: the u*y half-dot uses no LDS -> compute before the barrier,
    // overlapping the staging drain.
    float suy = 0.f;
    if (isL1) {
        float s2 = 0.f, s3 = 0.f;
#pragma unroll 4
        for (int k = 0; k < 256; k += 2) {
            float4 x0 = u4[k + 0], q0 = y4[k + 0];
            float4 x1 = u4[k + 1], q1 = y4[k + 1];
            s2 += x0.x * q0.x + x0.y * q0.y + x0.z * q0.z + x0.w * q0.w;
            s3 += x1.x * q1.x + x1.y * q1.y + x1.z * q1.z + x1.w * q1.w;
        }
        suy = s2 + s3;
    }
    __syncthreads();

    // w*h dot from LDS (first 2 iterations use prefetched weights)
    const float4* h4 = reinterpret_cast<const float4*>(&hs[b][0]);
    float s0, s1, s2, s3;
    {
        float4 v0 = h4[0], v1 = h4[1];
        s0 = pw0.x * v0.x + pw0.y * v0.y + pw0.z * v0.z + pw0.w * v0.w;
        s1 = pw1.x * v1.x + pw1.y * v1.y + pw1.z * v1.z + pw1.w * v1.w;
        s2 = 0.f; s3 = 0.f;
    }
#pragma unroll 4
    for (int k = 2; k < 256; k += 2) {
        float4 w0 = w4[k + 0], v0 = h4[k + 0];
        float4 w1 = w4[k + 1], v1 = h4[k + 1];
        s2 += w0.x * v0.x + w0.y * v0.y + w0.z * v0.z + w0.w * v0.w;
        s3 += w1.x * v1.x + w1.y * v1.y + w1.z * v1.z + w1.w * v1.w;
    }
    float s = (s0 + s1) + (s2 + s3);
    if (!isL1) {
        s += xp0[((size_t)t * B_ + b) * H4_ + grow];
    } else {
        s += suy + bih1[grow] + bhh1[grow];
    }
    gl[tid] = s;
    __syncthreads();

    if (tid < 64) {
        int jl2 = tid >> 4;
        int b2 = tid & 15;
        int jh2 = (bxl << 2) + jl2;
        float iv = gl[tid];
        float fv = gl[64 + tid];
        float gv = gl[128 + tid];
        float ov = gl[192 + tid];
        iv = 1.f / (1.f + __expf(-iv));
        fv = 1.f / (1.f + __expf(-fv));
        gv = tanhf(gv);
        ov = 1.f / (1.f + __expf(-ov));
        int ci = b2 * H_ + jh2;
        float cn = fv * cst[ci] + iv * gv;
        float hn = ov * tanhf(cn);
        cst[ci] = cn;
        hout[ci] = hn;
        if (!isL1) {
            y0[((size_t)t * B_ + b2) * H_ + jh2] = hn;
        } else {
            outb[((size_t)b2 * T_ + t) * H_ + jh2] = f2bf(hn);
        }
    }
}

// ---------------------------------------------------------------------------
// Final state copy: d_out tail = h_n[2][B][H], c_n[2][B][H]
// ---------------------------------------------------------------------------
__global__ __launch_bounds__(256) void copy_states(const float* __restrict__ h0,
                                                   const float* __restrict__ h1,
                                                   const float* __restrict__ c0,
                                                   const float* __restrict__ c1,
                                                   float* __restrict__ dst) {
    int i = blockIdx.x * blockDim.x + threadIdx.x;  // 0..16383
    dst[i] = h0[i];
    dst[16384 + i] = h1[i];
    dst[32768 + i] = c0[i];
    dst[49152 + i] = c1[i];
}

// ---------------------------------------------------------------------------
extern "C" void kernel_launch(void* const* d_in, const int* in_sizes, int n_in,
                              void* d_out, int out_size, void* d_ws,
                              size_t ws_size, hipStream_t stream) {
    const int* x = (const int*)d_in[0];
    const float* emb = (const float*)d_in[1];
    const float* Wih0 = (const float*)d_in[2];
    const float* Whh0 = (const float*)d_in[3];
    const float* bih0 = (const float*)d_in[4];
    const float* bhh0 = (const float*)d_in[5];
    const float* Wih1 = (const float*)d_in[6];
    const float* Whh1 = (const float*)d_in[7];
    const float* bih1 = (const float*)d_in[8];
    const float* bhh1 = (const float*)d_in[9];
    const float* fcW = (const float*)d_in[10];
    const float* fcb = (const float*)d_in[11];

    char* ws = (char*)d_ws;
    size_t off = 0;
    auto alloc = [&](size_t bytes) {
        size_t o = off;
        off = (off + bytes + 255) & ~(size_t)255;
        return o;
    };
    ushort* fcWb  = (ushort*)(ws + alloc((size_t)V_ * H_ * 2));   // 64 MB
    ushort* wih0b = (ushort*)(ws + alloc((size_t)H4_ * E_ * 2));  //  4 MB
    ushort* a0    = (ushort*)(ws + alloc((size_t)BT_ * E_ * 2));  //  4 MB
    ushort* outb  = (ushort*)(ws + alloc((size_t)BT_ * H_ * 2));  //  8 MB
    float*  xp    = (float*)(ws + alloc((size_t)BT_ * H4_ * 4));  // 64 MB
    float*  y0f   = (float*)(ws + alloc((size_t)BT_ * H_ * 4));   // 16 MB
    float*  states = (float*)(ws + alloc(6 * (size_t)B_ * H_ * 4));
    float* ha0 = states;
    float* hb0 = states + 1 * B_ * H_;
    float* c0s = states + 2 * B_ * H_;
    float* ha1 = states + 3 * B_ * H_;
    float* hb1 = states + 4 * B_ * H_;
    float* c1s = states + 5 * B_ * H_;

    // zero h/c state (ws is poisoned 0xAA before every call)
    hipMemsetAsync(states, 0, 6 * (size_t)B_ * H_ * 4, stream);

    // weight conversions to bf16 (GEMM operands only)
    cvt_bf16<<<2048, 256, 0, stream>>>(Wih0, wih0b, (H4_ * E_) / 4);
    cvt_bf16<<<4096, 256, 0, stream>>>(fcW, fcWb, (V_ * H_) / 4);

    // embedding gather -> A0 (bf16, row t*B+b)
    embed_k<<<BT_, 128, 0, stream>>>(x, emb, a0);

    // xp0 = A0 @ Wih0^T + (bih0+bhh0)   [M=4096, N=4096, K=512]
    gemm_bt<<<dim3(BT_ / 128, H4_ / 128), 256, 0, stream>>>(
        a0, wih0b, bih0, bhh0, xp, BT_, H4_, E_);

    // diagonal recurrence: dispatch d runs L0 t=d and L1 t=d-1
    for (int d = 0; d <= T_; ++d) {
        lstm_diag<<<512, 256, 0, stream>>>(xp, Whh0, ha0, hb0, c0s, y0f,
                                           Whh1, Wih1, bih1, bhh1, ha1, hb1,
                                           c1s, outb, d);
    }
    // t=255 (odd) wrote ha0 / ha1

    // logits = out @ fcW^T + fcb   [M=4096, N=32000, K=1024]
    // M-tiles on the fast axis: B-panel reuse across the 32 M-tiles.
    gemm_bt<<<dim3(BT_ / 128, V_ / 128), 256, 0, stream>>>(
        outb, fcWb, fcb, nullptr, (float*)d_out, BT_, V_, H_);

    // h_n / c_n tail
    copy_states<<<64, 256, 0, stream>>>(ha0, ha1, c0s, c1s,
                                        (float*)d_out + LOGITS_N);
}